// Round 1
// baseline (878.741 us; speedup 1.0000x reference)
//
#include <hip/hip_runtime.h>
#include <math.h>

#define NSEQ 2048
#define NB 4
#define NH 8
#define DH 64
#define DMODEL 512
// rows of the (b,n) flattened activation matrix
#define MROWS (NSEQ * NB)

// ---------------------------------------------------------------------------
// Kernel 1: fused QKV projection + RoPE.
// C[m][nn] = xb[m][:] . Wcat[nn][:]  with m = bi*NSEQ + ni, xb[m] = x[ni][bi]
// nn in [0,1536): [0,512)=Q, [512,1024)=K, [1024,1536)=V
// Outputs Q/K/V in (b, h, n, dh) layout. RoPE applied to Q and K.
// 64x64 tile, BK=16, 256 threads, 4x4 micro-tile, LDS stored K-major so the
// inner loop reads are ds_read_b128.
// ---------------------------------------------------------------------------
__global__ __launch_bounds__(256) void k1_qkv_rope(
    const float* __restrict__ x, const float* __restrict__ rope,
    const float* __restrict__ Wq, const float* __restrict__ Wk,
    const float* __restrict__ Wv,
    float* __restrict__ Qw, float* __restrict__ Kw, float* __restrict__ Vw)
{
    __shared__ float As[16][68];   // [k][row], stride 68 => 16B-aligned float4 rows
    __shared__ float Bs[16][68];   // [k][col]
    const int t = threadIdx.x;
    const int row0 = blockIdx.x * 64;
    const int col0g = blockIdx.y * 64;
    const int ty = t >> 4, tx = t & 15;
    const int lr = t >> 2;            // 0..63 tile row for loads
    const int lk = (t & 3) << 2;      // 0,4,8,12 k-offset for loads

    const int m_l = row0 + lr;
    const int bi_l = m_l >> 11;
    const int ni_l = m_l & (NSEQ - 1);
    const float* xrow = x + ((size_t)(ni_l * NB + bi_l)) * DMODEL;

    const int nn_l = col0g + lr;
    const float* wrow;
    if (nn_l < 512)       wrow = Wq + (size_t)nn_l * DMODEL;
    else if (nn_l < 1024) wrow = Wk + (size_t)(nn_l - 512) * DMODEL;
    else                  wrow = Wv + (size_t)(nn_l - 1024) * DMODEL;

    float acc[4][4] = {};
    for (int k0 = 0; k0 < DMODEL; k0 += 16) {
        float4 a4 = *(const float4*)(xrow + k0 + lk);
        float4 b4 = *(const float4*)(wrow + k0 + lk);
        As[lk + 0][lr] = a4.x; As[lk + 1][lr] = a4.y;
        As[lk + 2][lr] = a4.z; As[lk + 3][lr] = a4.w;
        Bs[lk + 0][lr] = b4.x; Bs[lk + 1][lr] = b4.y;
        Bs[lk + 2][lr] = b4.z; Bs[lk + 3][lr] = b4.w;
        __syncthreads();
#pragma unroll
        for (int kk = 0; kk < 16; ++kk) {
            float4 av = *(const float4*)&As[kk][ty << 2];
            float4 bv = *(const float4*)&Bs[kk][tx << 2];
            float a[4] = {av.x, av.y, av.z, av.w};
            float b[4] = {bv.x, bv.y, bv.z, bv.w};
#pragma unroll
            for (int i = 0; i < 4; ++i)
#pragma unroll
                for (int j = 0; j < 4; ++j)
                    acc[i][j] = fmaf(a[i], b[j], acc[i][j]);
        }
        __syncthreads();
    }

    // Epilogue: RoPE (for Q/K regions) + scatter to (b,h,n,dh)
    const int c0 = col0g + (tx << 2);
    const int region = c0 >> 9;       // 0=Q 1=K 2=V
    const int cm = c0 & 511;
    const int h = cm >> 6;
    const int e = cm & 63;            // within-head dim, multiple of 4 (pairs aligned)
    float* outp = (region == 0) ? Qw : ((region == 1) ? Kw : Vw);
#pragma unroll
    for (int i = 0; i < 4; ++i) {
        const int m = row0 + (ty << 2) + i;
        const int bi = m >> 11, ni = m & (NSEQ - 1);
        float v0 = acc[i][0], v1 = acc[i][1], v2 = acc[i][2], v3 = acc[i][3];
        if (region < 2) {
            const float4 f4 = *(const float4*)(rope + ((size_t)(bi * NSEQ + ni)) * DH + e);
            // out[2i]   = t[2i]*cos(f[2i])   - t[2i+1]*sin(f[2i])
            // out[2i+1] = t[2i+1]*cos(f[2i+1]) + t[2i]*sin(f[2i+1])
            float r0 = v0 * cosf(f4.x) - v1 * sinf(f4.x);
            float r1 = v1 * cosf(f4.y) + v0 * sinf(f4.y);
            float r2 = v2 * cosf(f4.z) - v3 * sinf(f4.z);
            float r3 = v3 * cosf(f4.w) + v2 * sinf(f4.w);
            v0 = r0; v1 = r1; v2 = r2; v3 = r3;
        }
        float4 st = make_float4(v0, v1, v2, v3);
        *(float4*)(outp + (((size_t)bi * NH + h) * NSEQ + ni) * DH + e) = st;
    }
}

// ---------------------------------------------------------------------------
// Kernel 2: causal flash attention, fp32.
// One block per (b, h, q-tile of 64). Online softmax over K/V tiles jt<=qt.
// S tile 64x64 kept in LDS (transposed [key][qrow] so PV A-reads are b128).
// Epilogue: /l, *head_scale, store O in (b, n, h*dh).
// ---------------------------------------------------------------------------
__global__ __launch_bounds__(256) void k2_attn(
    const float* __restrict__ Qw, const float* __restrict__ Kw,
    const float* __restrict__ Vw, const float* __restrict__ head_scale,
    float* __restrict__ Ow)
{
    const int qt = (int)(gridDim.x - 1) - (int)blockIdx.x;  // big tiles first
    const int bh = blockIdx.y;
    const int bi = bh >> 3, h = bh & 7;

    __shared__ float sQt[64][68];   // Q^T  [dh][qrow]
    __shared__ float sKt[64][68];   // K^T  [dh][krow]
    __shared__ float sV [64][68];   // V    [krow][dh]
    __shared__ float sSt[64][68];   // S^T/P^T [krow][qrow]
    __shared__ float sM[64], sL[64], sAlpha[64];
    __shared__ float sRed[64][4], sRed2[64][4];

    const int t = threadIdx.x;
    const int ty = t >> 4, tx = t & 15;
    const int sr = t >> 2;   // softmax row
    const int sq = t & 3;    // softmax quarter

    const size_t base = ((size_t)bi * NH + h) * (size_t)NSEQ * DH;

    // load Q tile transposed
#pragma unroll
    for (int u = 0; u < 4; ++u) {
        int off = (t + u * 256) << 2;
        int r = off >> 6, c = off & 63;
        float4 v4 = *(const float4*)(Qw + base + (size_t)qt * 64 * DH + off);
        sQt[c + 0][r] = v4.x; sQt[c + 1][r] = v4.y;
        sQt[c + 2][r] = v4.z; sQt[c + 3][r] = v4.w;
    }
    if (t < 64) { sM[t] = -1e30f; sL[t] = 0.f; }
    float acc[4][4] = {};

    for (int jt = 0; jt <= qt; ++jt) {
        __syncthreads();   // prior PV reads of sKt/sV/sSt complete (and Q/init on iter 0)
#pragma unroll
        for (int u = 0; u < 4; ++u) {
            int off = (t + u * 256) << 2;
            int r = off >> 6, c = off & 63;
            float4 kv = *(const float4*)(Kw + base + (size_t)jt * 64 * DH + off);
            sKt[c + 0][r] = kv.x; sKt[c + 1][r] = kv.y;
            sKt[c + 2][r] = kv.z; sKt[c + 3][r] = kv.w;
            float4 vv = *(const float4*)(Vw + base + (size_t)jt * 64 * DH + off);
            *(float4*)&sV[r][c] = vv;
        }
        __syncthreads();

        // S = (Q K^T) * scale, causal mask on the diagonal tile
        float s[4][4] = {};
#pragma unroll 8
        for (int d = 0; d < 64; ++d) {
            float4 av = *(const float4*)&sQt[d][ty << 2];
            float4 bv = *(const float4*)&sKt[d][tx << 2];
            float a[4] = {av.x, av.y, av.z, av.w};
            float b[4] = {bv.x, bv.y, bv.z, bv.w};
#pragma unroll
            for (int i = 0; i < 4; ++i)
#pragma unroll
                for (int j = 0; j < 4; ++j)
                    s[i][j] = fmaf(a[i], b[j], s[i][j]);
        }
        const bool diag = (jt == qt);
#pragma unroll
        for (int i = 0; i < 4; ++i) {
            const int qi = (qt << 6) + (ty << 2) + i;
#pragma unroll
            for (int j = 0; j < 4; ++j) {
                const int kj = (jt << 6) + (tx << 2) + j;
                float val = s[i][j] * 0.125f;
                if (diag && kj > qi) val = -1e30f;
                sSt[(tx << 2) + j][(ty << 2) + i] = val;
            }
        }
        __syncthreads();

        // online softmax: 4 threads per row, 16 cols each
        {
            const float m_old = sM[sr];
            float lm = m_old;
#pragma unroll
            for (int c = 0; c < 16; ++c)
                lm = fmaxf(lm, sSt[(sq << 4) + c][sr]);
            sRed[sr][sq] = lm;
            __syncthreads();
            const float m_new = fmaxf(fmaxf(sRed[sr][0], sRed[sr][1]),
                                      fmaxf(sRed[sr][2], sRed[sr][3]));
            const float alpha = __expf(m_old - m_new);
            float lsum = 0.f;
#pragma unroll
            for (int c = 0; c < 16; ++c) {
                const int cc = (sq << 4) + c;
                const float p = __expf(sSt[cc][sr] - m_new);
                sSt[cc][sr] = p;
                lsum += p;
            }
            sRed2[sr][sq] = lsum;
            if (sq == 0) { sM[sr] = m_new; sAlpha[sr] = alpha; }
            __syncthreads();
            if (sq == 0) {
                sL[sr] = sL[sr] * alpha +
                         (sRed2[sr][0] + sRed2[sr][1] + sRed2[sr][2] + sRed2[sr][3]);
            }
        }

        // O = O*alpha + P @ V
        float al[4];
#pragma unroll
        for (int i = 0; i < 4; ++i) al[i] = sAlpha[(ty << 2) + i];
#pragma unroll
        for (int i = 0; i < 4; ++i)
#pragma unroll
            for (int j = 0; j < 4; ++j) acc[i][j] *= al[i];
#pragma unroll 8
        for (int d = 0; d < 64; ++d) {
            float4 av = *(const float4*)&sSt[d][ty << 2];   // P^T[key=d][qrow]
            float4 bv = *(const float4*)&sV[d][tx << 2];    // V[key=d][dh]
            float a[4] = {av.x, av.y, av.z, av.w};
            float b[4] = {bv.x, bv.y, bv.z, bv.w};
#pragma unroll
            for (int i = 0; i < 4; ++i)
#pragma unroll
                for (int j = 0; j < 4; ++j)
                    acc[i][j] = fmaf(a[i], b[j], acc[i][j]);
        }
    }
    __syncthreads();   // sL final

    const float hs = head_scale[h];
#pragma unroll
    for (int i = 0; i < 4; ++i) {
        const int qi = (qt << 6) + (ty << 2) + i;
        const float f = hs / sL[(ty << 2) + i];
        float4 st = make_float4(acc[i][0] * f, acc[i][1] * f,
                                acc[i][2] * f, acc[i][3] * f);
        *(float4*)(Ow + ((size_t)bi * NSEQ + qi) * DMODEL + h * DH + (tx << 2)) = st;
    }
}

// ---------------------------------------------------------------------------
// Kernel 3: out projection  C2[m][c] = O[m][:] . Wo[c][:] + bo[c]
// ---------------------------------------------------------------------------
__global__ __launch_bounds__(256) void k3_proj(
    const float* __restrict__ Ow, const float* __restrict__ Wo,
    const float* __restrict__ bo, float* __restrict__ C2)
{
    __shared__ float As[16][68];
    __shared__ float Bs[16][68];
    const int t = threadIdx.x;
    const int row0 = blockIdx.x * 64;
    const int col0 = blockIdx.y * 64;
    const int ty = t >> 4, tx = t & 15;
    const int lr = t >> 2;
    const int lk = (t & 3) << 2;

    const float* arow = Ow + (size_t)(row0 + lr) * DMODEL;
    const float* wrow = Wo + (size_t)(col0 + lr) * DMODEL;

    float acc[4][4] = {};
    for (int k0 = 0; k0 < DMODEL; k0 += 16) {
        float4 a4 = *(const float4*)(arow + k0 + lk);
        float4 b4 = *(const float4*)(wrow + k0 + lk);
        As[lk + 0][lr] = a4.x; As[lk + 1][lr] = a4.y;
        As[lk + 2][lr] = a4.z; As[lk + 3][lr] = a4.w;
        Bs[lk + 0][lr] = b4.x; Bs[lk + 1][lr] = b4.y;
        Bs[lk + 2][lr] = b4.z; Bs[lk + 3][lr] = b4.w;
        __syncthreads();
#pragma unroll
        for (int kk = 0; kk < 16; ++kk) {
            float4 av = *(const float4*)&As[kk][ty << 2];
            float4 bv = *(const float4*)&Bs[kk][tx << 2];
            float a[4] = {av.x, av.y, av.z, av.w};
            float b[4] = {bv.x, bv.y, bv.z, bv.w};
#pragma unroll
            for (int i = 0; i < 4; ++i)
#pragma unroll
                for (int j = 0; j < 4; ++j)
                    acc[i][j] = fmaf(a[i], b[j], acc[i][j]);
        }
        __syncthreads();
    }
    const int c = col0 + (tx << 2);
    const float4 bo4 = *(const float4*)(bo + c);
#pragma unroll
    for (int i = 0; i < 4; ++i) {
        const int m = row0 + (ty << 2) + i;
        float4 st = make_float4(acc[i][0] + bo4.x, acc[i][1] + bo4.y,
                                acc[i][2] + bo4.z, acc[i][3] + bo4.w);
        *(float4*)(C2 + (size_t)m * DMODEL + c) = st;
    }
}

// ---------------------------------------------------------------------------
// Kernel 4: LayerNorm over dim 512 + ls_scale + transpose store to (n,b,d)
// ---------------------------------------------------------------------------
__global__ __launch_bounds__(256) void k4_ln(
    const float* __restrict__ C2, const float* __restrict__ g,
    const float* __restrict__ bln, const float* __restrict__ ls,
    float* __restrict__ out)
{
    const int m = blockIdx.x;
    const int bi = m >> 11, ni = m & (NSEQ - 1);
    const float* row = C2 + (size_t)m * DMODEL;
    const int t = threadIdx.x;
    float v0 = row[t], v1 = row[t + 256];
    float s = v0 + v1, sq2 = v0 * v0 + v1 * v1;
#pragma unroll
    for (int off = 32; off > 0; off >>= 1) {
        s += __shfl_down(s, off);
        sq2 += __shfl_down(sq2, off);
    }
    __shared__ float red[8];
    const int wid = t >> 6;
    if ((t & 63) == 0) { red[wid] = s; red[wid + 4] = sq2; }
    __syncthreads();
    s = red[0] + red[1] + red[2] + red[3];
    sq2 = red[4] + red[5] + red[6] + red[7];
    const float mean = s * (1.f / 512.f);
    const float var = sq2 * (1.f / 512.f) - mean * mean;
    const float rstd = rsqrtf(var + 1e-5f);
    float* ob = out + ((size_t)ni * NB + bi) * DMODEL;
    ob[t]       = ((v0 - mean) * rstd * g[t]       + bln[t])       * ls[t];
    ob[t + 256] = ((v1 - mean) * rstd * g[t + 256] + bln[t + 256]) * ls[t + 256];
}

// ---------------------------------------------------------------------------
extern "C" void kernel_launch(void* const* d_in, const int* in_sizes, int n_in,
                              void* d_out, int out_size, void* d_ws, size_t ws_size,
                              hipStream_t stream) {
    const float* x          = (const float*)d_in[0];
    const float* rope       = (const float*)d_in[1];
    const float* Wq         = (const float*)d_in[2];
    const float* Wk         = (const float*)d_in[3];
    const float* Wv         = (const float*)d_in[4];
    const float* Wo         = (const float*)d_in[5];
    const float* bo         = (const float*)d_in[6];
    const float* ln_g       = (const float*)d_in[7];
    const float* ln_b       = (const float*)d_in[8];
    const float* head_scale = (const float*)d_in[9];
    const float* ls_scale   = (const float*)d_in[10];
    float* out = (float*)d_out;

    float* ws = (float*)d_ws;
    const size_t SZ = (size_t)NB * NH * NSEQ * DH;   // 4194304 floats = 16 MB
    float* Qw = ws;
    float* Kw = ws + SZ;
    float* Vw = ws + 2 * SZ;
    float* Ow = ws + 3 * SZ;
    float* C2 = Qw;   // reuse: Q dead after attention

    k1_qkv_rope<<<dim3(MROWS / 64, 1536 / 64), 256, 0, stream>>>(
        x, rope, Wq, Wk, Wv, Qw, Kw, Vw);
    k2_attn<<<dim3(NSEQ / 64, NB * NH), 256, 0, stream>>>(
        Qw, Kw, Vw, head_scale, Ow);
    k3_proj<<<dim3(MROWS / 64, DMODEL / 64), 256, 0, stream>>>(Ow, Wo, bo, C2);
    k4_ln<<<MROWS, 256, 0, stream>>>(C2, ln_g, ln_b, ls_scale, out);
}

// Round 2
// 549.307 us; speedup vs baseline: 1.5997x; 1.5997x over previous
//
#include <hip/hip_runtime.h>
#include <hip/hip_bf16.h>
#include <math.h>

#define NSEQ 2048
#define NB 4
#define NH 8
#define DH 64
#define DMODEL 512
#define MROWS (NSEQ * NB)

typedef short bf16x8 __attribute__((ext_vector_type(8)));
typedef float f32x4 __attribute__((ext_vector_type(4)));

static __device__ __forceinline__ short f2bf(float f) {
    __hip_bfloat16 h = __float2bfloat16(f);
    return *reinterpret_cast<short*>(&h);
}

// ---------------------------------------------------------------------------
// Kernel 1: fused QKV projection + RoPE. fp32 GEMM (64x64 tile, 4x4 micro),
// epilogue converts to bf16: Q,K -> (b,h,n,dh) with RoPE; V -> transposed
// (b,h,dh,n) so k2's PV B-fragments are contiguous 16B reads.
// ---------------------------------------------------------------------------
__global__ __launch_bounds__(256) void k1_qkv_rope(
    const float* __restrict__ x, const float* __restrict__ rope,
    const float* __restrict__ Wq, const float* __restrict__ Wk,
    const float* __restrict__ Wv,
    __hip_bfloat16* __restrict__ Qw, __hip_bfloat16* __restrict__ Kw,
    __hip_bfloat16* __restrict__ Vt)
{
    __shared__ float As[16][68];
    __shared__ float Bs[16][68];
    const int t = threadIdx.x;
    const int row0 = blockIdx.x * 64;
    const int col0g = blockIdx.y * 64;
    const int ty = t >> 4, tx = t & 15;
    const int lr = t >> 2;
    const int lk = (t & 3) << 2;

    const int m_l = row0 + lr;
    const int bi_l = m_l >> 11;
    const int ni_l = m_l & (NSEQ - 1);
    const float* xrow = x + ((size_t)(ni_l * NB + bi_l)) * DMODEL;

    const int nn_l = col0g + lr;
    const float* wrow;
    if (nn_l < 512)       wrow = Wq + (size_t)nn_l * DMODEL;
    else if (nn_l < 1024) wrow = Wk + (size_t)(nn_l - 512) * DMODEL;
    else                  wrow = Wv + (size_t)(nn_l - 1024) * DMODEL;

    float acc[4][4] = {};
    for (int k0 = 0; k0 < DMODEL; k0 += 16) {
        float4 a4 = *(const float4*)(xrow + k0 + lk);
        float4 b4 = *(const float4*)(wrow + k0 + lk);
        As[lk + 0][lr] = a4.x; As[lk + 1][lr] = a4.y;
        As[lk + 2][lr] = a4.z; As[lk + 3][lr] = a4.w;
        Bs[lk + 0][lr] = b4.x; Bs[lk + 1][lr] = b4.y;
        Bs[lk + 2][lr] = b4.z; Bs[lk + 3][lr] = b4.w;
        __syncthreads();
#pragma unroll
        for (int kk = 0; kk < 16; ++kk) {
            float4 av = *(const float4*)&As[kk][ty << 2];
            float4 bv = *(const float4*)&Bs[kk][tx << 2];
            float a[4] = {av.x, av.y, av.z, av.w};
            float b[4] = {bv.x, bv.y, bv.z, bv.w};
#pragma unroll
            for (int i = 0; i < 4; ++i)
#pragma unroll
                for (int j = 0; j < 4; ++j)
                    acc[i][j] = fmaf(a[i], b[j], acc[i][j]);
        }
        __syncthreads();
    }

    const int c0 = col0g + (tx << 2);
    const int region = c0 >> 9;       // 0=Q 1=K 2=V
    const int cm = c0 & 511;
    const int h = cm >> 6;
    const int e = cm & 63;
    const int bi = row0 >> 11;                    // whole block same batch
    const int ni0 = (row0 & (NSEQ - 1)) + (ty << 2);

    if (region < 2) {
        __hip_bfloat16* outp = (region == 0) ? Qw : Kw;
#pragma unroll
        for (int i = 0; i < 4; ++i) {
            const int ni = ni0 + i;
            const float4 f4 = *(const float4*)(rope + ((size_t)(bi * NSEQ + ni)) * DH + e);
            float v0 = acc[i][0], v1 = acc[i][1], v2 = acc[i][2], v3 = acc[i][3];
            float r0 = v0 * cosf(f4.x) - v1 * sinf(f4.x);
            float r1 = v1 * cosf(f4.y) + v0 * sinf(f4.y);
            float r2 = v2 * cosf(f4.z) - v3 * sinf(f4.z);
            float r3 = v3 * cosf(f4.w) + v2 * sinf(f4.w);
            short4 st;
            st.x = f2bf(r0); st.y = f2bf(r1); st.z = f2bf(r2); st.w = f2bf(r3);
            *reinterpret_cast<short4*>(outp + (((size_t)bi * NH + h) * NSEQ + ni) * DH + e) = st;
        }
    } else {
        // V transposed: Vt[(bh)*DH + d][n]
#pragma unroll
        for (int j = 0; j < 4; ++j) {
            short4 st;
            st.x = f2bf(acc[0][j]); st.y = f2bf(acc[1][j]);
            st.z = f2bf(acc[2][j]); st.w = f2bf(acc[3][j]);
            *reinterpret_cast<short4*>(Vt + (((size_t)bi * NH + h) * DH + e + j) * NSEQ + ni0) = st;
        }
    }
}

// ---------------------------------------------------------------------------
// Kernel 2: causal flash attention, bf16 MFMA (16x16x32), fp32 accumulate.
// One wave owns 16 q-rows; 4 independent waves per block (no __syncthreads).
// Per 64-key tile: 8 MFMA QK^T (K B-frags direct from global, L1/L2-served),
// log2-domain online softmax (shuffle reductions across the 16-lane group),
// P -> bf16 via per-wave LDS round-trip (stride 72 bf16: ds_read_b128 hits
// all 32 banks exactly 8x = conflict-free minimum), 8 MFMA PV from V^T.
// ---------------------------------------------------------------------------
__global__ __launch_bounds__(256) void k2_attn_mfma(
    const __hip_bfloat16* __restrict__ Qw, const __hip_bfloat16* __restrict__ Kw,
    const __hip_bfloat16* __restrict__ Vt, const float* __restrict__ head_scale,
    float* __restrict__ Ow)
{
    __shared__ short sP[4][16][72];   // per-wave P buffer, 2304 B each

    const int t = threadIdx.x;
    const int w = t >> 6;
    const int L = t & 63;
    const int lo = L & 15;            // A-frag m / C-frag col / B-frag n
    const int g = L >> 4;             // quad

    const int bh = blockIdx.y;
    const int bi = bh >> 3, h = bh & 7;
    const int qg = (int)(gridDim.x - 1 - blockIdx.x);   // big tiles first
    const int qt = (qg << 2) + w;     // q-tile of 16 rows
    const int q0 = qt << 4;

    const size_t baseQK = (size_t)bh * (NSEQ * DH);
    const size_t baseVt = (size_t)bh * (DH * NSEQ);

    // Q A-fragments (row m = lo, k = g*8 + j), once per wave
    const __hip_bfloat16* qp = Qw + baseQK + (size_t)(q0 + lo) * DH + (g << 3);
    const bf16x8 qa0 = *(const bf16x8*)(qp);
    const bf16x8 qa1 = *(const bf16x8*)(qp + 32);

    f32x4 acc[4] = {{0.f,0.f,0.f,0.f},{0.f,0.f,0.f,0.f},
                    {0.f,0.f,0.f,0.f},{0.f,0.f,0.f,0.f}};
    float m_i[4] = {-1e30f, -1e30f, -1e30f, -1e30f};
    float l_i[4] = {0.f, 0.f, 0.f, 0.f};

    const int nkt = (qt >> 2) + 1;    // key tiles of 64
    const float SC = 0.125f * 1.44269504088896f;   // scale * log2(e)

    for (int kt = 0; kt < nkt; ++kt) {
        const int k0 = kt << 6;

        // --- S = Q K^T (4 n-tiles of 16 keys, K-dim 64 = 2 MFMA steps) ---
        f32x4 s[4];
#pragma unroll
        for (int nt = 0; nt < 4; ++nt) {
            const __hip_bfloat16* kp =
                Kw + baseQK + (size_t)(k0 + (nt << 4) + lo) * DH + (g << 3);
            bf16x8 b0 = *(const bf16x8*)(kp);
            bf16x8 b1 = *(const bf16x8*)(kp + 32);
            f32x4 z = {0.f, 0.f, 0.f, 0.f};
            z = __builtin_amdgcn_mfma_f32_16x16x32_bf16(qa0, b0, z, 0, 0, 0);
            s[nt] = __builtin_amdgcn_mfma_f32_16x16x32_bf16(qa1, b1, z, 0, 0, 0);
        }

        // --- scale to log2 domain + causal mask (diagonal tile only) ---
        const bool diag = (kt == nkt - 1);
#pragma unroll
        for (int nt = 0; nt < 4; ++nt) {
#pragma unroll
            for (int r = 0; r < 4; ++r) {
                float v = s[nt][r] * SC;
                if (diag) {
                    const int row = q0 + (g << 2) + r;
                    const int col = k0 + (nt << 4) + lo;
                    if (col > row) v = -1e30f;
                }
                s[nt][r] = v;
            }
        }

        // --- online softmax (rows live in 16-lane groups) ---
        float mt[4];
#pragma unroll
        for (int r = 0; r < 4; ++r)
            mt[r] = fmaxf(fmaxf(s[0][r], s[1][r]), fmaxf(s[2][r], s[3][r]));
#pragma unroll
        for (int off = 1; off < 16; off <<= 1) {
#pragma unroll
            for (int r = 0; r < 4; ++r)
                mt[r] = fmaxf(mt[r], __shfl_xor(mt[r], off));
        }
        float alpha[4];
#pragma unroll
        for (int r = 0; r < 4; ++r) {
            const float mnew = fmaxf(m_i[r], mt[r]);
            alpha[r] = exp2f(m_i[r] - mnew);
            m_i[r] = mnew;
        }
        float rs[4] = {0.f, 0.f, 0.f, 0.f};
#pragma unroll
        for (int nt = 0; nt < 4; ++nt) {
#pragma unroll
            for (int r = 0; r < 4; ++r) {
                const float p = exp2f(s[nt][r] - m_i[r]);
                rs[r] += p;
                sP[w][(g << 2) + r][(nt << 4) + lo] = f2bf(p);
            }
        }
#pragma unroll
        for (int off = 1; off < 16; off <<= 1) {
#pragma unroll
            for (int r = 0; r < 4; ++r)
                rs[r] += __shfl_xor(rs[r], off);
        }
#pragma unroll
        for (int r = 0; r < 4; ++r)
            l_i[r] = l_i[r] * alpha[r] + rs[r];
#pragma unroll
        for (int dt = 0; dt < 4; ++dt)
#pragma unroll
            for (int r = 0; r < 4; ++r)
                acc[dt][r] *= alpha[r];

        // --- O += P V : P A-frags from LDS, V B-frags from V^T (global) ---
        const bf16x8 pa0 = *(const bf16x8*)&sP[w][lo][(g << 3)];
        const bf16x8 pa1 = *(const bf16x8*)&sP[w][lo][32 + (g << 3)];
#pragma unroll
        for (int dt = 0; dt < 4; ++dt) {
            const __hip_bfloat16* vp =
                Vt + baseVt + (size_t)((dt << 4) + lo) * NSEQ + k0 + (g << 3);
            bf16x8 vb0 = *(const bf16x8*)(vp);
            bf16x8 vb1 = *(const bf16x8*)(vp + 32);
            acc[dt] = __builtin_amdgcn_mfma_f32_16x16x32_bf16(pa0, vb0, acc[dt], 0, 0, 0);
            acc[dt] = __builtin_amdgcn_mfma_f32_16x16x32_bf16(pa1, vb1, acc[dt], 0, 0, 0);
        }
    }

    // --- epilogue: /l, *head_scale, fp32 store to Ow (b, n, h*dh) ---
    const float hs = head_scale[h];
#pragma unroll
    for (int r = 0; r < 4; ++r) {
        const int row = q0 + (g << 2) + r;
        const float f = hs / l_i[r];
        float* op = Ow + ((size_t)bi * NSEQ + row) * DMODEL + (h << 6) + lo;
#pragma unroll
        for (int dt = 0; dt < 4; ++dt)
            op[dt << 4] = acc[dt][r] * f;
    }
}

// ---------------------------------------------------------------------------
// Kernel 3: out projection  C2[m][c] = O[m][:] . Wo[c][:] + bo[c]  (fp32)
// ---------------------------------------------------------------------------
__global__ __launch_bounds__(256) void k3_proj(
    const float* __restrict__ Ow, const float* __restrict__ Wo,
    const float* __restrict__ bo, float* __restrict__ C2)
{
    __shared__ float As[16][68];
    __shared__ float Bs[16][68];
    const int t = threadIdx.x;
    const int row0 = blockIdx.x * 64;
    const int col0 = blockIdx.y * 64;
    const int ty = t >> 4, tx = t & 15;
    const int lr = t >> 2;
    const int lk = (t & 3) << 2;

    const float* arow = Ow + (size_t)(row0 + lr) * DMODEL;
    const float* wrow = Wo + (size_t)(col0 + lr) * DMODEL;

    float acc[4][4] = {};
    for (int k0 = 0; k0 < DMODEL; k0 += 16) {
        float4 a4 = *(const float4*)(arow + k0 + lk);
        float4 b4 = *(const float4*)(wrow + k0 + lk);
        As[lk + 0][lr] = a4.x; As[lk + 1][lr] = a4.y;
        As[lk + 2][lr] = a4.z; As[lk + 3][lr] = a4.w;
        Bs[lk + 0][lr] = b4.x; Bs[lk + 1][lr] = b4.y;
        Bs[lk + 2][lr] = b4.z; Bs[lk + 3][lr] = b4.w;
        __syncthreads();
#pragma unroll
        for (int kk = 0; kk < 16; ++kk) {
            float4 av = *(const float4*)&As[kk][ty << 2];
            float4 bv = *(const float4*)&Bs[kk][tx << 2];
            float a[4] = {av.x, av.y, av.z, av.w};
            float b[4] = {bv.x, bv.y, bv.z, bv.w};
#pragma unroll
            for (int i = 0; i < 4; ++i)
#pragma unroll
                for (int j = 0; j < 4; ++j)
                    acc[i][j] = fmaf(a[i], b[j], acc[i][j]);
        }
        __syncthreads();
    }
    const int c = col0 + (tx << 2);
    const float4 bo4 = *(const float4*)(bo + c);
#pragma unroll
    for (int i = 0; i < 4; ++i) {
        const int m = row0 + (ty << 2) + i;
        float4 st = make_float4(acc[i][0] + bo4.x, acc[i][1] + bo4.y,
                                acc[i][2] + bo4.z, acc[i][3] + bo4.w);
        *(float4*)(C2 + (size_t)m * DMODEL + c) = st;
    }
}

// ---------------------------------------------------------------------------
// Kernel 4: LayerNorm over dim 512 + ls_scale + transpose store to (n,b,d)
// ---------------------------------------------------------------------------
__global__ __launch_bounds__(256) void k4_ln(
    const float* __restrict__ C2, const float* __restrict__ g,
    const float* __restrict__ bln, const float* __restrict__ ls,
    float* __restrict__ out)
{
    const int m = blockIdx.x;
    const int bi = m >> 11, ni = m & (NSEQ - 1);
    const float* row = C2 + (size_t)m * DMODEL;
    const int t = threadIdx.x;
    float v0 = row[t], v1 = row[t + 256];
    float s = v0 + v1, sq2 = v0 * v0 + v1 * v1;
#pragma unroll
    for (int off = 32; off > 0; off >>= 1) {
        s += __shfl_down(s, off);
        sq2 += __shfl_down(sq2, off);
    }
    __shared__ float red[8];
    const int wid = t >> 6;
    if ((t & 63) == 0) { red[wid] = s; red[wid + 4] = sq2; }
    __syncthreads();
    s = red[0] + red[1] + red[2] + red[3];
    sq2 = red[4] + red[5] + red[6] + red[7];
    const float mean = s * (1.f / 512.f);
    const float var = sq2 * (1.f / 512.f) - mean * mean;
    const float rstd = rsqrtf(var + 1e-5f);
    float* ob = out + ((size_t)ni * NB + bi) * DMODEL;
    ob[t]       = ((v0 - mean) * rstd * g[t]       + bln[t])       * ls[t];
    ob[t + 256] = ((v1 - mean) * rstd * g[t + 256] + bln[t + 256]) * ls[t + 256];
}

// ---------------------------------------------------------------------------
extern "C" void kernel_launch(void* const* d_in, const int* in_sizes, int n_in,
                              void* d_out, int out_size, void* d_ws, size_t ws_size,
                              hipStream_t stream) {
    const float* x          = (const float*)d_in[0];
    const float* rope       = (const float*)d_in[1];
    const float* Wq         = (const float*)d_in[2];
    const float* Wk         = (const float*)d_in[3];
    const float* Wv         = (const float*)d_in[4];
    const float* Wo         = (const float*)d_in[5];
    const float* bo         = (const float*)d_in[6];
    const float* ln_g       = (const float*)d_in[7];
    const float* ln_b       = (const float*)d_in[8];
    const float* head_scale = (const float*)d_in[9];
    const float* ls_scale   = (const float*)d_in[10];
    float* out = (float*)d_out;

    char* wsb = (char*)d_ws;
    __hip_bfloat16* Qw = (__hip_bfloat16*)(wsb);                       // 8 MB
    __hip_bfloat16* Kw = (__hip_bfloat16*)(wsb + ((size_t)8 << 20));   // 8 MB
    __hip_bfloat16* Vt = (__hip_bfloat16*)(wsb + ((size_t)16 << 20));  // 8 MB
    float*          Ow = (float*)(wsb + ((size_t)24 << 20));           // 16 MB
    float*          C2 = (float*)(wsb);   // 16 MB, overlaps Q/K (dead after k2)

    k1_qkv_rope<<<dim3(MROWS / 64, 1536 / 64), 256, 0, stream>>>(
        x, rope, Wq, Wk, Wv, Qw, Kw, Vt);
    k2_attn_mfma<<<dim3(NSEQ / 64, NB * NH), 256, 0, stream>>>(
        Qw, Kw, Vt, head_scale, Ow);
    k3_proj<<<dim3(MROWS / 64, DMODEL / 64), 256, 0, stream>>>(Ow, Wo, bo, C2);
    k4_ln<<<MROWS, 256, 0, stream>>>(C2, ln_g, ln_b, ls_scale, out);
}

// Round 3
// 240.830 us; speedup vs baseline: 3.6488x; 2.2809x over previous
//
#include <hip/hip_runtime.h>
#include <hip/hip_bf16.h>
#include <math.h>

#define NSEQ 2048
#define NB 4
#define NH 8
#define DH 64
#define DMODEL 512
#define MROWS (NSEQ * NB)

typedef short bf16x8 __attribute__((ext_vector_type(8)));
typedef float f32x4 __attribute__((ext_vector_type(4)));

static __device__ __forceinline__ short f2bf(float f) {
    __hip_bfloat16 h = __float2bfloat16(f);
    return *reinterpret_cast<short*>(&h);
}

// ---------------------------------------------------------------------------
// Kernel 1: QKV projection, bf16 MFMA (16x16x32), 128x128 tile, BK=32.
// fp32 inputs converted to bf16 during LDS staging. Epilogue: RoPE (partner
// element via shfl_xor(v,1)), softmax scale folded into Q, scatter to
// Q/K (b,h,n,dh) and V transposed (b,h,dh,n) in bf16.
// LDS pitch 40 shorts (80 B): 16B-aligned rows, ~2-way banks (free).
// ---------------------------------------------------------------------------
__global__ __launch_bounds__(256) void k1_qkv(
    const float* __restrict__ x, const float* __restrict__ rope,
    const float* __restrict__ Wq, const float* __restrict__ Wk,
    const float* __restrict__ Wv,
    __hip_bfloat16* __restrict__ Qw, __hip_bfloat16* __restrict__ Kw,
    __hip_bfloat16* __restrict__ Vt)
{
    __shared__ short As[128][40];
    __shared__ short Bs[128][40];
    const int t = threadIdx.x;
    const int w = t >> 6, L = t & 63, lo = L & 15, g = L >> 4;
    const int mh = (w >> 1) << 6, nh = (w & 1) << 6;
    const int row0 = blockIdx.x * 128, col0 = blockIdx.y * 128;
    const int bi = row0 >> 11, ni0 = row0 & (NSEQ - 1);
    const int region = col0 >> 9;          // 0=Q 1=K 2=V (whole block uniform)
    const int cbase = col0 & 511;
    const float* Wsrc = (region == 0 ? Wq : (region == 1 ? Wk : Wv))
                        + (size_t)cbase * DMODEL;

    f32x4 acc[4][4] = {};
    for (int it = 0; it < 16; ++it) {
        const int k0 = it << 5;
        __syncthreads();
#pragma unroll
        for (int c = 0; c < 4; ++c) {
            const int idx = c * 256 + t;
            const int m = idx >> 3, kc = idx & 7;
            float4 av = *(const float4*)(x + ((size_t)((ni0 + m) * NB + bi)) * DMODEL + k0 + kc * 4);
            short4 a4 = { f2bf(av.x), f2bf(av.y), f2bf(av.z), f2bf(av.w) };
            *(short4*)&As[m][kc * 4] = a4;
            float4 bv = *(const float4*)(Wsrc + (size_t)m * DMODEL + k0 + kc * 4);
            short4 b4 = { f2bf(bv.x), f2bf(bv.y), f2bf(bv.z), f2bf(bv.w) };
            *(short4*)&Bs[m][kc * 4] = b4;
        }
        __syncthreads();
        bf16x8 af[4], bfr[4];
#pragma unroll
        for (int mi = 0; mi < 4; ++mi)
            af[mi] = *(const bf16x8*)&As[mh + mi * 16 + lo][g * 8];
#pragma unroll
        for (int ni = 0; ni < 4; ++ni)
            bfr[ni] = *(const bf16x8*)&Bs[nh + ni * 16 + lo][g * 8];
#pragma unroll
        for (int mi = 0; mi < 4; ++mi)
#pragma unroll
            for (int ni = 0; ni < 4; ++ni)
                acc[mi][ni] = __builtin_amdgcn_mfma_f32_16x16x32_bf16(
                    af[mi], bfr[ni], acc[mi][ni], 0, 0, 0);
    }

    const float SC = 0.125f * 1.44269504088896f;   // attn scale * log2(e), folded into Q
    if (region < 2) {
        __hip_bfloat16* outp = (region == 0) ? Qw : Kw;
        const float qs = (region == 0) ? SC : 1.0f;
#pragma unroll
        for (int ni = 0; ni < 4; ++ni) {
            const int c = cbase + nh + ni * 16 + lo;
            const int h = c >> 6, e = c & 63;
            const float sgn = (e & 1) ? 1.0f : -1.0f;
#pragma unroll
            for (int mi = 0; mi < 4; ++mi) {
#pragma unroll
                for (int r = 0; r < 4; ++r) {
                    const int nseq = ni0 + mh + mi * 16 + g * 4 + r;
                    const float f = rope[((size_t)bi * NSEQ + nseq) * DH + e];
                    const float v = acc[mi][ni][r];
                    const float p = __shfl_xor(v, 1);   // rotate-half partner
                    const float rv = (v * __cosf(f) + sgn * p * __sinf(f)) * qs;
                    outp[((size_t)(bi * NH + h) * NSEQ + nseq) * DH + e] = __float2bfloat16(rv);
                }
            }
        }
    } else {
        // V transposed: Vt[(b*NH+h)*DH + d][nseq]; 4 consecutive nseq per store
#pragma unroll
        for (int ni = 0; ni < 4; ++ni) {
            const int c = cbase + nh + ni * 16 + lo;
            const int h = c >> 6, e = c & 63;
#pragma unroll
            for (int mi = 0; mi < 4; ++mi) {
                const int nb = ni0 + mh + mi * 16 + g * 4;
                short4 s4 = { f2bf(acc[mi][ni][0]), f2bf(acc[mi][ni][1]),
                              f2bf(acc[mi][ni][2]), f2bf(acc[mi][ni][3]) };
                *(short4*)(Vt + ((size_t)(bi * NH + h) * DH + e) * NSEQ + nb) = s4;
            }
        }
    }
}

// ---------------------------------------------------------------------------
// Kernel 2: causal flash attention, bf16 MFMA, LDS-staged K/V shared by the
// 4 waves of a 64-q-row block (same key range for all). Computes S^T = K.Q^T
// so the softmax key-reduction is 15 in-lane fmax + 2 shuffles. Q pre-scaled
// (log2 domain). Fully-masked diagonal sub-tiles skipped. O stored bf16.
// ---------------------------------------------------------------------------
__global__ __launch_bounds__(256) void k2_attn(
    const __hip_bfloat16* __restrict__ Qw, const __hip_bfloat16* __restrict__ Kw,
    const __hip_bfloat16* __restrict__ Vt, const float* __restrict__ head_scale,
    __hip_bfloat16* __restrict__ Ob)
{
    __shared__ short sK[64][72];      // [key][dh]   (72 pitch: 16B-aligned, 2-way)
    __shared__ short sV[64][72];      // [d][key]    (d-major, from Vt)
    __shared__ short sP[4][16][72];   // per-wave P [q][key]
    __shared__ float sA[4][16];
    __shared__ float sLl[4][16];

    const int t = threadIdx.x;
    const int w = t >> 6, L = t & 63, lo = L & 15, g = L >> 4;
    const int bh = blockIdx.y;
    const int bi = bh >> 3, h = bh & 7;
    const int qg = (int)(gridDim.x - 1 - blockIdx.x);   // big blocks first
    const int q0 = qg << 6;
    const int qw = q0 + (w << 4);

    const size_t baseQK = (size_t)bh * (NSEQ * DH);
    const size_t baseV  = (size_t)bh * (DH * NSEQ);

    // Q B-fragments (n=q=lo, k=dh=g*8+j), once per wave
    const __hip_bfloat16* qp = Qw + baseQK + (size_t)(qw + lo) * DH + (g << 3);
    const bf16x8 qb0 = *(const bf16x8*)(qp);
    const bf16x8 qb1 = *(const bf16x8*)(qp + 32);

    f32x4 acc[4] = {};
    float m_i = -1e30f, l_i = 0.f;

    const int nkt = qg + 1;
    for (int kt = 0; kt < nkt; ++kt) {
        const int k0 = kt << 6;
        __syncthreads();
#pragma unroll
        for (int c = 0; c < 2; ++c) {
            const int idx = c * 256 + t;
            const int m = idx >> 3, kb = idx & 7;
            *(uint4*)&sK[m][kb * 8] =
                *(const uint4*)(Kw + baseQK + (size_t)(k0 + m) * DH + kb * 8);
            *(uint4*)&sV[m][kb * 8] =
                *(const uint4*)(Vt + baseV + (size_t)m * NSEQ + k0 + kb * 8);
        }
        __syncthreads();

        const bool diag = (kt == qg);
        const int mlim = diag ? w : 3;     // skip fully-masked 16-key tiles
        f32x4 s[4];
#pragma unroll
        for (int mt = 0; mt < 4; ++mt) {
            if (mt <= mlim) {
                bf16x8 ka0 = *(const bf16x8*)&sK[mt * 16 + lo][g * 8];
                bf16x8 ka1 = *(const bf16x8*)&sK[mt * 16 + lo][32 + g * 8];
                f32x4 z = {};
                z = __builtin_amdgcn_mfma_f32_16x16x32_bf16(ka0, qb0, z, 0, 0, 0);
                s[mt] = __builtin_amdgcn_mfma_f32_16x16x32_bf16(ka1, qb1, z, 0, 0, 0);
                if (diag && mt == mlim) {
#pragma unroll
                    for (int r = 0; r < 4; ++r)
                        if ((g * 4 + r) > lo) s[mt][r] = -1e30f;
                }
            } else {
                s[mt] = (f32x4){ -1e30f, -1e30f, -1e30f, -1e30f };
            }
        }

        // online softmax: lane owns q=lo; keys spread over (mt, r, quad)
        float mx = s[0][0];
#pragma unroll
        for (int mt = 0; mt < 4; ++mt)
#pragma unroll
            for (int r = 0; r < 4; ++r)
                mx = fmaxf(mx, s[mt][r]);
        mx = fmaxf(mx, __shfl_xor(mx, 16));
        mx = fmaxf(mx, __shfl_xor(mx, 32));
        const float mnew = fmaxf(m_i, mx);
        const float alpha = exp2f(m_i - mnew);
        m_i = mnew;
        float rs = 0.f;
#pragma unroll
        for (int mt = 0; mt < 4; ++mt) {
            const float p0 = exp2f(s[mt][0] - mnew);
            const float p1 = exp2f(s[mt][1] - mnew);
            const float p2 = exp2f(s[mt][2] - mnew);
            const float p3 = exp2f(s[mt][3] - mnew);
            rs += (p0 + p1) + (p2 + p3);
            short4 pw4 = { f2bf(p0), f2bf(p1), f2bf(p2), f2bf(p3) };
            *(short4*)&sP[w][lo][mt * 16 + g * 4] = pw4;   // P[q][key], 4 keys
        }
        rs += __shfl_xor(rs, 16);
        rs += __shfl_xor(rs, 32);
        l_i = l_i * alpha + rs;
        if (g == 0) sA[w][lo] = alpha;
        const f32x4 al = *(const f32x4*)&sA[w][g * 4];   // alpha per acc-row

#pragma unroll
        for (int dt = 0; dt < 4; ++dt) acc[dt] *= al;

        const bf16x8 pa0 = *(const bf16x8*)&sP[w][lo][g * 8];
        const bool skip_hi = diag && (w < 2);   // keys 32..63 all masked
        if (!skip_hi) {
            const bf16x8 pa1 = *(const bf16x8*)&sP[w][lo][32 + g * 8];
#pragma unroll
            for (int dt = 0; dt < 4; ++dt) {
                bf16x8 vb0 = *(const bf16x8*)&sV[dt * 16 + lo][g * 8];
                bf16x8 vb1 = *(const bf16x8*)&sV[dt * 16 + lo][32 + g * 8];
                acc[dt] = __builtin_amdgcn_mfma_f32_16x16x32_bf16(pa0, vb0, acc[dt], 0, 0, 0);
                acc[dt] = __builtin_amdgcn_mfma_f32_16x16x32_bf16(pa1, vb1, acc[dt], 0, 0, 0);
            }
        } else {
#pragma unroll
            for (int dt = 0; dt < 4; ++dt) {
                bf16x8 vb0 = *(const bf16x8*)&sV[dt * 16 + lo][g * 8];
                acc[dt] = __builtin_amdgcn_mfma_f32_16x16x32_bf16(pa0, vb0, acc[dt], 0, 0, 0);
            }
        }
    }

    if (g == 0) sLl[w][lo] = l_i;
    const f32x4 lv = *(const f32x4*)&sLl[w][g * 4];
    const float hs = head_scale[h];
#pragma unroll
    for (int r = 0; r < 4; ++r) {
        const int q = q0 + (w << 4) + g * 4 + r;
        const float f = hs / lv[r];
#pragma unroll
        for (int dt = 0; dt < 4; ++dt)
            Ob[((size_t)bi * NSEQ + q) * DMODEL + h * DH + dt * 16 + lo] =
                __float2bfloat16(acc[dt][r] * f);
    }
}

// ---------------------------------------------------------------------------
// Kernel 3: out projection, bf16 MFMA, same 128x128 skeleton as k1.
// A = Ob (bf16, staged directly); B = Wo (fp32, converted during staging).
// ---------------------------------------------------------------------------
__global__ __launch_bounds__(256) void k3_proj(
    const __hip_bfloat16* __restrict__ Ob, const float* __restrict__ Wo,
    const float* __restrict__ bo, float* __restrict__ C2)
{
    __shared__ short As[128][40];
    __shared__ short Bs[128][40];
    const int t = threadIdx.x;
    const int w = t >> 6, L = t & 63, lo = L & 15, g = L >> 4;
    const int mh = (w >> 1) << 6, nh = (w & 1) << 6;
    const int row0 = blockIdx.x * 128, col0 = blockIdx.y * 128;

    f32x4 acc[4][4] = {};
    for (int it = 0; it < 16; ++it) {
        const int k0 = it << 5;
        __syncthreads();
#pragma unroll
        for (int c = 0; c < 2; ++c) {
            const int idx = c * 256 + t;
            const int m = idx >> 2, kb = idx & 3;
            *(uint4*)&As[m][kb * 8] =
                *(const uint4*)(Ob + (size_t)(row0 + m) * DMODEL + k0 + kb * 8);
        }
#pragma unroll
        for (int c = 0; c < 4; ++c) {
            const int idx = c * 256 + t;
            const int m = idx >> 3, kc = idx & 7;
            float4 bv = *(const float4*)(Wo + (size_t)(col0 + m) * DMODEL + k0 + kc * 4);
            short4 b4 = { f2bf(bv.x), f2bf(bv.y), f2bf(bv.z), f2bf(bv.w) };
            *(short4*)&Bs[m][kc * 4] = b4;
        }
        __syncthreads();
        bf16x8 af[4], bfr[4];
#pragma unroll
        for (int mi = 0; mi < 4; ++mi)
            af[mi] = *(const bf16x8*)&As[mh + mi * 16 + lo][g * 8];
#pragma unroll
        for (int ni = 0; ni < 4; ++ni)
            bfr[ni] = *(const bf16x8*)&Bs[nh + ni * 16 + lo][g * 8];
#pragma unroll
        for (int mi = 0; mi < 4; ++mi)
#pragma unroll
            for (int ni = 0; ni < 4; ++ni)
                acc[mi][ni] = __builtin_amdgcn_mfma_f32_16x16x32_bf16(
                    af[mi], bfr[ni], acc[mi][ni], 0, 0, 0);
    }
#pragma unroll
    for (int ni = 0; ni < 4; ++ni) {
        const int c = col0 + nh + ni * 16 + lo;
        const float b = bo[c];
#pragma unroll
        for (int mi = 0; mi < 4; ++mi) {
#pragma unroll
            for (int r = 0; r < 4; ++r) {
                const int m = row0 + mh + mi * 16 + g * 4 + r;
                C2[(size_t)m * DMODEL + c] = acc[mi][ni][r] + b;
            }
        }
    }
}

// ---------------------------------------------------------------------------
// Kernel 4: LayerNorm over dim 512 + ls_scale + transpose store to (n,b,d)
// ---------------------------------------------------------------------------
__global__ __launch_bounds__(256) void k4_ln(
    const float* __restrict__ C2, const float* __restrict__ g,
    const float* __restrict__ bln, const float* __restrict__ ls,
    float* __restrict__ out)
{
    const int m = blockIdx.x;
    const int bi = m >> 11, ni = m & (NSEQ - 1);
    const float* row = C2 + (size_t)m * DMODEL;
    const int t = threadIdx.x;
    float v0 = row[t], v1 = row[t + 256];
    float s = v0 + v1, sq2 = v0 * v0 + v1 * v1;
#pragma unroll
    for (int off = 32; off > 0; off >>= 1) {
        s += __shfl_down(s, off);
        sq2 += __shfl_down(sq2, off);
    }
    __shared__ float red[8];
    const int wid = t >> 6;
    if ((t & 63) == 0) { red[wid] = s; red[wid + 4] = sq2; }
    __syncthreads();
    s = red[0] + red[1] + red[2] + red[3];
    sq2 = red[4] + red[5] + red[6] + red[7];
    const float mean = s * (1.f / 512.f);
    const float var = sq2 * (1.f / 512.f) - mean * mean;
    const float rstd = rsqrtf(var + 1e-5f);
    float* ob = out + ((size_t)ni * NB + bi) * DMODEL;
    ob[t]       = ((v0 - mean) * rstd * g[t]       + bln[t])       * ls[t];
    ob[t + 256] = ((v1 - mean) * rstd * g[t + 256] + bln[t + 256]) * ls[t + 256];
}

// ---------------------------------------------------------------------------
extern "C" void kernel_launch(void* const* d_in, const int* in_sizes, int n_in,
                              void* d_out, int out_size, void* d_ws, size_t ws_size,
                              hipStream_t stream) {
    const float* x          = (const float*)d_in[0];
    const float* rope       = (const float*)d_in[1];
    const float* Wq         = (const float*)d_in[2];
    const float* Wk         = (const float*)d_in[3];
    const float* Wv         = (const float*)d_in[4];
    const float* Wo         = (const float*)d_in[5];
    const float* bo         = (const float*)d_in[6];
    const float* ln_g       = (const float*)d_in[7];
    const float* ln_b       = (const float*)d_in[8];
    const float* head_scale = (const float*)d_in[9];
    const float* ls_scale   = (const float*)d_in[10];
    float* out = (float*)d_out;

    char* wsb = (char*)d_ws;
    __hip_bfloat16* Qw = (__hip_bfloat16*)(wsb);                       // 8 MB
    __hip_bfloat16* Kw = (__hip_bfloat16*)(wsb + ((size_t)8 << 20));   // 8 MB
    __hip_bfloat16* Vt = (__hip_bfloat16*)(wsb + ((size_t)16 << 20));  // 8 MB
    __hip_bfloat16* Ob = (__hip_bfloat16*)(wsb + ((size_t)24 << 20));  // 8 MB
    float*          C2 = (float*)(wsb);   // 16 MB, overlaps Q/K (dead after k2)

    k1_qkv<<<dim3(MROWS / 128, 1536 / 128), 256, 0, stream>>>(
        x, rope, Wq, Wk, Wv, Qw, Kw, Vt);
    k2_attn<<<dim3(NSEQ / 64, NB * NH), 256, 0, stream>>>(
        Qw, Kw, Vt, head_scale, Ob);
    k3_proj<<<dim3(MROWS / 128, DMODEL / 128), 256, 0, stream>>>(Ob, Wo, bo, C2);
    k4_ln<<<MROWS, 256, 0, stream>>>(C2, ln_g, ln_b, ls_scale, out);
}

// Round 4
// 230.708 us; speedup vs baseline: 3.8089x; 1.0439x over previous
//
#include <hip/hip_runtime.h>
#include <hip/hip_bf16.h>
#include <math.h>

#define NSEQ 2048
#define NB 4
#define NH 8
#define DH 64
#define DMODEL 512
#define MROWS (NSEQ * NB)

typedef short bf16x8 __attribute__((ext_vector_type(8)));
typedef float f32x4 __attribute__((ext_vector_type(4)));

// fast RNE fp32->bf16 (3 int ops; same rounding as __float2bfloat16 for
// non-NaN inputs, which is all we have here)
static __device__ __forceinline__ short f2bf_r(float f) {
    unsigned u = __float_as_uint(f);
    u += 0x7FFF + ((u >> 16) & 1);
    return (short)(u >> 16);
}
static __device__ __forceinline__ unsigned bfpack(float a, float b) {
    unsigned ua = __float_as_uint(a); ua += 0x7FFF + ((ua >> 16) & 1);
    unsigned ub = __float_as_uint(b); ub += 0x7FFF + ((ub >> 16) & 1);
    return (ua >> 16) | (ub & 0xFFFF0000u);
}

// ---------------------------------------------------------------------------
// Kernel 0: one-shot fp32->bf16 conversion.
//   xb[b*2048+n][d]  <- x[n][b][d]      (8192x512)
//   Wb rows 0..511=Wq, 512..1023=Wk, 1024..1535=Wv, 1536..2047=Wo  (2048x512)
// ---------------------------------------------------------------------------
__global__ __launch_bounds__(256) void k0_convert(
    const float* __restrict__ x, const float* __restrict__ Wq,
    const float* __restrict__ Wk, const float* __restrict__ Wv,
    const float* __restrict__ Wo,
    __hip_bfloat16* __restrict__ xb, __hip_bfloat16* __restrict__ Wb)
{
    const int idx = blockIdx.x * 256 + threadIdx.x;
    if (idx < 8192 * 128) {
        const int row = idx >> 7, c = (idx & 127) << 2;
        const int bi = row >> 11, ni = row & 2047;
        float4 v = *(const float4*)(x + ((size_t)(ni * NB + bi)) * DMODEL + c);
        uint2 u; u.x = bfpack(v.x, v.y); u.y = bfpack(v.z, v.w);
        *(uint2*)((short*)xb + (size_t)row * 512 + c) = u;
    } else {
        const int j = idx - 8192 * 128;
        const int row = j >> 7, c = (j & 127) << 2;
        const float* src = (row < 512) ? Wq : (row < 1024) ? Wk
                         : (row < 1536) ? Wv : Wo;
        const int rr = row & 511;
        float4 v = *(const float4*)(src + (size_t)rr * 512 + c);
        uint2 u; u.x = bfpack(v.x, v.y); u.y = bfpack(v.z, v.w);
        *(uint2*)((short*)Wb + (size_t)row * 512 + c) = u;
    }
}

// ---------------------------------------------------------------------------
// Kernel 1: QKV projection, pure-bf16 MFMA GEMM. 128x128 tile, BK=64,
// uint4 staging (no conversions in hot loop), LDS pitch 72 shorts (144 B:
// bank-group rotation 1 -> staging writes and frag reads both spread
// 8 lanes/group = b128 minimum). Epilogue: RoPE + scatter (unchanged math).
// ---------------------------------------------------------------------------
__global__ __launch_bounds__(256) void k1_qkv(
    const __hip_bfloat16* __restrict__ xb, const float* __restrict__ rope,
    const __hip_bfloat16* __restrict__ Wb,
    __hip_bfloat16* __restrict__ Qw, __hip_bfloat16* __restrict__ Kw,
    __hip_bfloat16* __restrict__ Vt)
{
    __shared__ short As[128 * 72];
    __shared__ short Bs[128 * 72];
    const int t = threadIdx.x;
    const int w = t >> 6, L = t & 63, lo = L & 15, g = L >> 4;
    const int mh = (w >> 1) << 6, nh = (w & 1) << 6;
    const int row0 = blockIdx.x * 128, col0 = blockIdx.y * 128;

    f32x4 acc[4][4] = {};
    for (int k0 = 0; k0 < DMODEL; k0 += 64) {
        __syncthreads();
#pragma unroll
        for (int c = 0; c < 4; ++c) {
            const int idx = c * 256 + t;
            const int m = idx >> 3, kb = idx & 7;
            *(uint4*)&As[m * 72 + kb * 8] =
                *(const uint4*)((const short*)xb + (size_t)(row0 + m) * 512 + k0 + kb * 8);
            *(uint4*)&Bs[m * 72 + kb * 8] =
                *(const uint4*)((const short*)Wb + (size_t)(col0 + m) * 512 + k0 + kb * 8);
        }
        __syncthreads();
#pragma unroll
        for (int ks = 0; ks < 2; ++ks) {
            bf16x8 af[4], bfr[4];
#pragma unroll
            for (int mi = 0; mi < 4; ++mi)
                af[mi] = *(const bf16x8*)&As[(mh + mi * 16 + lo) * 72 + ks * 32 + g * 8];
#pragma unroll
            for (int ni = 0; ni < 4; ++ni)
                bfr[ni] = *(const bf16x8*)&Bs[(nh + ni * 16 + lo) * 72 + ks * 32 + g * 8];
#pragma unroll
            for (int mi = 0; mi < 4; ++mi)
#pragma unroll
                for (int ni = 0; ni < 4; ++ni)
                    acc[mi][ni] = __builtin_amdgcn_mfma_f32_16x16x32_bf16(
                        af[mi], bfr[ni], acc[mi][ni], 0, 0, 0);
        }
    }

    const int region = col0 >> 9;          // 0=Q 1=K 2,3=V
    const int cbase = col0 & 511;
    const int bi = row0 >> 11;
    const int ni0 = row0 & 2047;
    const float SC = 0.125f * 1.44269504088896f;   // attn scale * log2(e) into Q
    if (region < 2) {
        __hip_bfloat16* outp = (region == 0) ? Qw : Kw;
        const float qs = (region == 0) ? SC : 1.0f;
#pragma unroll
        for (int ni = 0; ni < 4; ++ni) {
            const int c = cbase + nh + ni * 16 + lo;
            const int h = c >> 6, e = c & 63;
            const float sgn = (e & 1) ? 1.0f : -1.0f;
#pragma unroll
            for (int mi = 0; mi < 4; ++mi) {
#pragma unroll
                for (int r = 0; r < 4; ++r) {
                    const int nseq = ni0 + mh + mi * 16 + g * 4 + r;
                    const float f = rope[((size_t)bi * NSEQ + nseq) * DH + e];
                    const float v = acc[mi][ni][r];
                    const float p = __shfl_xor(v, 1);   // rotate-half partner
                    const float rv = (v * __cosf(f) + sgn * p * __sinf(f)) * qs;
                    *((short*)outp + ((size_t)(bi * NH + h) * NSEQ + nseq) * DH + e) = f2bf_r(rv);
                }
            }
        }
    } else {
        // V transposed: Vt[(b*NH+h)*DH + d][nseq]
#pragma unroll
        for (int ni = 0; ni < 4; ++ni) {
            const int c = cbase + nh + ni * 16 + lo;
            const int h = c >> 6, e = c & 63;
#pragma unroll
            for (int mi = 0; mi < 4; ++mi) {
                const int nb = ni0 + mh + mi * 16 + g * 4;
                uint2 u;
                u.x = bfpack(acc[mi][ni][0], acc[mi][ni][1]);
                u.y = bfpack(acc[mi][ni][2], acc[mi][ni][3]);
                *(uint2*)((short*)Vt + ((size_t)(bi * NH + h) * DH + e) * NSEQ + nb) = u;
            }
        }
    }
}

// ---------------------------------------------------------------------------
// Kernel 2: causal flash attention, bf16 MFMA. Balanced pairing: block
// (pair, bh) processes q-tiles {pair, 31-pair} -> every block = 33 key-tiles.
// Double-buffered K/V LDS staging with register prefetch: ONE barrier/tile,
// global latency hidden under MFMA+softmax. Fast bf16 packing.
// ---------------------------------------------------------------------------
__global__ __launch_bounds__(256) void k2_attn(
    const __hip_bfloat16* __restrict__ Qw, const __hip_bfloat16* __restrict__ Kw,
    const __hip_bfloat16* __restrict__ Vt, const float* __restrict__ head_scale,
    __hip_bfloat16* __restrict__ Ob)
{
    __shared__ short sK[2][64 * 72];
    __shared__ short sV[2][64 * 72];
    __shared__ short sP[4][16 * 72];
    __shared__ float sA[4][16];
    __shared__ float sLl[4][16];

    const int t = threadIdx.x;
    const int w = t >> 6, L = t & 63, lo = L & 15, g = L >> 4;
    const int bh = blockIdx.y, bi = bh >> 3, h = bh & 7;
    const size_t baseQK = (size_t)bh * (NSEQ * DH);
    const size_t baseV  = (size_t)bh * (DH * NSEQ);
    const float hs = head_scale[h];
    const int sm = t >> 3, skb = t & 7;   // staging: row sm(+32c), 16B chunk skb

#pragma unroll 1
    for (int phase = 0; phase < 2; ++phase) {
        const int qg = phase ? 31 - (int)blockIdx.x : (int)blockIdx.x;
        const int q0 = qg << 6;
        const int qw16 = q0 + (w << 4);
        const __hip_bfloat16* qp = Qw + baseQK + (size_t)(qw16 + lo) * DH + g * 8;
        const bf16x8 qb0 = *(const bf16x8*)qp;
        const bf16x8 qb1 = *(const bf16x8*)(qp + 32);
        f32x4 acc[4] = {};
        float m_i = -1e30f, l_i = 0.f;
        const int nkt = qg + 1;

        // preload tile 0 into regs, then buffer 0
        uint4 kr[2], vr[2];
#pragma unroll
        for (int c = 0; c < 2; ++c) {
            const int m = sm + c * 32;
            kr[c] = *(const uint4*)((const short*)Kw + baseQK + (size_t)m * DH + skb * 8);
            vr[c] = *(const uint4*)((const short*)Vt + baseV + (size_t)m * NSEQ + skb * 8);
        }
        __syncthreads();   // protect buffers still being read by prior phase
#pragma unroll
        for (int c = 0; c < 2; ++c) {
            const int m = sm + c * 32;
            *(uint4*)&sK[0][m * 72 + skb * 8] = kr[c];
            *(uint4*)&sV[0][m * 72 + skb * 8] = vr[c];
        }

        for (int kt = 0; kt < nkt; ++kt) {
            const int cur = kt & 1;
            if (kt + 1 < nkt) {   // prefetch next tile into regs
                const int k0n = (kt + 1) << 6;
#pragma unroll
                for (int c = 0; c < 2; ++c) {
                    const int m = sm + c * 32;
                    kr[c] = *(const uint4*)((const short*)Kw + baseQK + (size_t)(k0n + m) * DH + skb * 8);
                    vr[c] = *(const uint4*)((const short*)Vt + baseV + (size_t)m * NSEQ + k0n + skb * 8);
                }
            }
            __syncthreads();   // buf[cur] fully written; prior reads of buf[cur^1] done

            const bool diag = (kt == qg);
            const int mlim = diag ? w : 3;
            f32x4 s[4];
#pragma unroll
            for (int mt = 0; mt < 4; ++mt) {
                if (mt <= mlim) {
                    bf16x8 ka0 = *(const bf16x8*)&sK[cur][(mt * 16 + lo) * 72 + g * 8];
                    bf16x8 ka1 = *(const bf16x8*)&sK[cur][(mt * 16 + lo) * 72 + 32 + g * 8];
                    f32x4 z = {};
                    z = __builtin_amdgcn_mfma_f32_16x16x32_bf16(ka0, qb0, z, 0, 0, 0);
                    s[mt] = __builtin_amdgcn_mfma_f32_16x16x32_bf16(ka1, qb1, z, 0, 0, 0);
                    if (diag && mt == mlim) {
#pragma unroll
                        for (int r = 0; r < 4; ++r)
                            if ((g * 4 + r) > lo) s[mt][r] = -1e30f;
                    }
                } else {
                    s[mt] = (f32x4){ -1e30f, -1e30f, -1e30f, -1e30f };
                }
            }

            // online softmax: lane owns q=lo; keys spread over (mt, r, quad)
            float mx = s[0][0];
#pragma unroll
            for (int mt = 0; mt < 4; ++mt)
#pragma unroll
                for (int r = 0; r < 4; ++r)
                    mx = fmaxf(mx, s[mt][r]);
            mx = fmaxf(mx, __shfl_xor(mx, 16));
            mx = fmaxf(mx, __shfl_xor(mx, 32));
            const float mnew = fmaxf(m_i, mx);
            const float alpha = exp2f(m_i - mnew);
            m_i = mnew;
            float rs = 0.f;
#pragma unroll
            for (int mt = 0; mt < 4; ++mt) {
                const float p0 = exp2f(s[mt][0] - mnew);
                const float p1 = exp2f(s[mt][1] - mnew);
                const float p2 = exp2f(s[mt][2] - mnew);
                const float p3 = exp2f(s[mt][3] - mnew);
                rs += (p0 + p1) + (p2 + p3);
                uint2 u; u.x = bfpack(p0, p1); u.y = bfpack(p2, p3);
                *(uint2*)&sP[w][lo * 72 + mt * 16 + g * 4] = u;
            }
            rs += __shfl_xor(rs, 16);
            rs += __shfl_xor(rs, 32);
            l_i = l_i * alpha + rs;
            if (g == 0) sA[w][lo] = alpha;
            const f32x4 al = *(const f32x4*)&sA[w][g * 4];
#pragma unroll
            for (int dt = 0; dt < 4; ++dt) acc[dt] *= al;

            const bf16x8 pa0 = *(const bf16x8*)&sP[w][lo * 72 + g * 8];
            if (!(diag && w < 2)) {
                const bf16x8 pa1 = *(const bf16x8*)&sP[w][lo * 72 + 32 + g * 8];
#pragma unroll
                for (int dt = 0; dt < 4; ++dt) {
                    bf16x8 vb0 = *(const bf16x8*)&sV[cur][(dt * 16 + lo) * 72 + g * 8];
                    bf16x8 vb1 = *(const bf16x8*)&sV[cur][(dt * 16 + lo) * 72 + 32 + g * 8];
                    acc[dt] = __builtin_amdgcn_mfma_f32_16x16x32_bf16(pa0, vb0, acc[dt], 0, 0, 0);
                    acc[dt] = __builtin_amdgcn_mfma_f32_16x16x32_bf16(pa1, vb1, acc[dt], 0, 0, 0);
                }
            } else {   // keys 32..63 fully masked on diagonal for waves 0,1
#pragma unroll
                for (int dt = 0; dt < 4; ++dt) {
                    bf16x8 vb0 = *(const bf16x8*)&sV[cur][(dt * 16 + lo) * 72 + g * 8];
                    acc[dt] = __builtin_amdgcn_mfma_f32_16x16x32_bf16(pa0, vb0, acc[dt], 0, 0, 0);
                }
            }

            if (kt + 1 < nkt) {   // write prefetched tile into the other buffer
#pragma unroll
                for (int c = 0; c < 2; ++c) {
                    const int m = sm + c * 32;
                    *(uint4*)&sK[cur ^ 1][m * 72 + skb * 8] = kr[c];
                    *(uint4*)&sV[cur ^ 1][m * 72 + skb * 8] = vr[c];
                }
            }
        }

        // per-phase epilogue
        if (g == 0) sLl[w][lo] = l_i;
        const f32x4 lv = *(const f32x4*)&sLl[w][g * 4];
#pragma unroll
        for (int r = 0; r < 4; ++r) {
            const int q = q0 + (w << 4) + g * 4 + r;
            const float f = hs / lv[r];
#pragma unroll
            for (int dt = 0; dt < 4; ++dt)
                *((short*)Ob + ((size_t)bi * NSEQ + q) * DMODEL + h * DH + dt * 16 + lo) =
                    f2bf_r(acc[dt][r] * f);
        }
    }
}

// ---------------------------------------------------------------------------
// Kernel 3: out projection, pure-bf16 MFMA, same skeleton as k1.
// ---------------------------------------------------------------------------
__global__ __launch_bounds__(256) void k3_proj(
    const __hip_bfloat16* __restrict__ Ob, const __hip_bfloat16* __restrict__ Wob,
    const float* __restrict__ bo, float* __restrict__ C2)
{
    __shared__ short As[128 * 72];
    __shared__ short Bs[128 * 72];
    const int t = threadIdx.x;
    const int w = t >> 6, L = t & 63, lo = L & 15, g = L >> 4;
    const int mh = (w >> 1) << 6, nh = (w & 1) << 6;
    const int row0 = blockIdx.x * 128, col0 = blockIdx.y * 128;

    f32x4 acc[4][4] = {};
    for (int k0 = 0; k0 < DMODEL; k0 += 64) {
        __syncthreads();
#pragma unroll
        for (int c = 0; c < 4; ++c) {
            const int idx = c * 256 + t;
            const int m = idx >> 3, kb = idx & 7;
            *(uint4*)&As[m * 72 + kb * 8] =
                *(const uint4*)((const short*)Ob + (size_t)(row0 + m) * 512 + k0 + kb * 8);
            *(uint4*)&Bs[m * 72 + kb * 8] =
                *(const uint4*)((const short*)Wob + (size_t)(col0 + m) * 512 + k0 + kb * 8);
        }
        __syncthreads();
#pragma unroll
        for (int ks = 0; ks < 2; ++ks) {
            bf16x8 af[4], bfr[4];
#pragma unroll
            for (int mi = 0; mi < 4; ++mi)
                af[mi] = *(const bf16x8*)&As[(mh + mi * 16 + lo) * 72 + ks * 32 + g * 8];
#pragma unroll
            for (int ni = 0; ni < 4; ++ni)
                bfr[ni] = *(const bf16x8*)&Bs[(nh + ni * 16 + lo) * 72 + ks * 32 + g * 8];
#pragma unroll
            for (int mi = 0; mi < 4; ++mi)
#pragma unroll
                for (int ni = 0; ni < 4; ++ni)
                    acc[mi][ni] = __builtin_amdgcn_mfma_f32_16x16x32_bf16(
                        af[mi], bfr[ni], acc[mi][ni], 0, 0, 0);
        }
    }
#pragma unroll
    for (int ni = 0; ni < 4; ++ni) {
        const int c = col0 + nh + ni * 16 + lo;
        const float b = bo[c];
#pragma unroll
        for (int mi = 0; mi < 4; ++mi) {
#pragma unroll
            for (int r = 0; r < 4; ++r) {
                const int m = row0 + mh + mi * 16 + g * 4 + r;
                C2[(size_t)m * DMODEL + c] = acc[mi][ni][r] + b;
            }
        }
    }
}

// ---------------------------------------------------------------------------
// Kernel 4: LayerNorm over dim 512 + ls_scale + transpose store to (n,b,d)
// ---------------------------------------------------------------------------
__global__ __launch_bounds__(256) void k4_ln(
    const float* __restrict__ C2, const float* __restrict__ g,
    const float* __restrict__ bln, const float* __restrict__ ls,
    float* __restrict__ out)
{
    const int m = blockIdx.x;
    const int bi = m >> 11, ni = m & (NSEQ - 1);
    const float* row = C2 + (size_t)m * DMODEL;
    const int t = threadIdx.x;
    float v0 = row[t], v1 = row[t + 256];
    float s = v0 + v1, sq2 = v0 * v0 + v1 * v1;
#pragma unroll
    for (int off = 32; off > 0; off >>= 1) {
        s += __shfl_down(s, off);
        sq2 += __shfl_down(sq2, off);
    }
    __shared__ float red[8];
    const int wid = t >> 6;
    if ((t & 63) == 0) { red[wid] = s; red[wid + 4] = sq2; }
    __syncthreads();
    s = red[0] + red[1] + red[2] + red[3];
    sq2 = red[4] + red[5] + red[6] + red[7];
    const float mean = s * (1.f / 512.f);
    const float var = sq2 * (1.f / 512.f) - mean * mean;
    const float rstd = rsqrtf(var + 1e-5f);
    float* ob = out + ((size_t)ni * NB + bi) * DMODEL;
    ob[t]       = ((v0 - mean) * rstd * g[t]       + bln[t])       * ls[t];
    ob[t + 256] = ((v1 - mean) * rstd * g[t + 256] + bln[t + 256]) * ls[t + 256];
}

// ---------------------------------------------------------------------------
extern "C" void kernel_launch(void* const* d_in, const int* in_sizes, int n_in,
                              void* d_out, int out_size, void* d_ws, size_t ws_size,
                              hipStream_t stream) {
    const float* x          = (const float*)d_in[0];
    const float* rope       = (const float*)d_in[1];
    const float* Wq         = (const float*)d_in[2];
    const float* Wk         = (const float*)d_in[3];
    const float* Wv         = (const float*)d_in[4];
    const float* Wo         = (const float*)d_in[5];
    const float* bo         = (const float*)d_in[6];
    const float* ln_g       = (const float*)d_in[7];
    const float* ln_b       = (const float*)d_in[8];
    const float* head_scale = (const float*)d_in[9];
    const float* ls_scale   = (const float*)d_in[10];
    float* out = (float*)d_out;

    char* wsb = (char*)d_ws;
    __hip_bfloat16* xb  = (__hip_bfloat16*)(wsb);                       // 8 MB
    __hip_bfloat16* Wb  = (__hip_bfloat16*)(wsb + ((size_t) 8 << 20));  // 2 MB
    __hip_bfloat16* Qw  = (__hip_bfloat16*)(wsb + ((size_t)10 << 20));  // 8 MB
    __hip_bfloat16* Kw  = (__hip_bfloat16*)(wsb + ((size_t)18 << 20));  // 8 MB
    __hip_bfloat16* Vt  = (__hip_bfloat16*)(wsb + ((size_t)26 << 20));  // 8 MB
    __hip_bfloat16* Ob  = (__hip_bfloat16*)(wsb + ((size_t)34 << 20));  // 8 MB
    float*          C2  = (float*)(wsb + ((size_t)10 << 20));           // 16 MB, overlaps Q/K
    __hip_bfloat16* Wob = Wb + (size_t)1536 * 512;

    k0_convert<<<5120, 256, 0, stream>>>(x, Wq, Wk, Wv, Wo, xb, Wb);
    k1_qkv<<<dim3(MROWS / 128, 1536 / 128), 256, 0, stream>>>(
        xb, rope, Wb, Qw, Kw, Vt);
    k2_attn<<<dim3(16, NB * NH), 256, 0, stream>>>(Qw, Kw, Vt, head_scale, Ob);
    k3_proj<<<dim3(MROWS / 128, DMODEL / 128), 256, 0, stream>>>(Ob, Wob, bo, C2);
    k4_ln<<<MROWS, 256, 0, stream>>>(C2, ln_g, ln_b, ls_scale, out);
}

// Round 5
// 223.324 us; speedup vs baseline: 3.9348x; 1.0331x over previous
//
#include <hip/hip_runtime.h>
#include <hip/hip_bf16.h>
#include <math.h>

#define NSEQ 2048
#define NB 4
#define NH 8
#define DH 64
#define DMODEL 512
#define MROWS (NSEQ * NB)

typedef short bf16x8 __attribute__((ext_vector_type(8)));
typedef float f32x4 __attribute__((ext_vector_type(4)));

// fast RNE fp32->bf16 (3 int ops; same rounding as __float2bfloat16 for
// non-NaN inputs, which is all we have here)
static __device__ __forceinline__ short f2bf_r(float f) {
    unsigned u = __float_as_uint(f);
    u += 0x7FFF + ((u >> 16) & 1);
    return (short)(u >> 16);
}
static __device__ __forceinline__ unsigned bfpack(float a, float b) {
    unsigned ua = __float_as_uint(a); ua += 0x7FFF + ((ua >> 16) & 1);
    unsigned ub = __float_as_uint(b); ub += 0x7FFF + ((ub >> 16) & 1);
    return (ua >> 16) | (ub & 0xFFFF0000u);
}

// ---------------------------------------------------------------------------
// Kernel 0: one-shot fp32->bf16 conversion.
//   xb[b*2048+n][d]  <- x[n][b][d]      (8192x512)
//   Wb rows 0..511=Wq, 512..1023=Wk, 1024..1535=Wv, 1536..2047=Wo  (2048x512)
// ---------------------------------------------------------------------------
__global__ __launch_bounds__(256) void k0_convert(
    const float* __restrict__ x, const float* __restrict__ Wq,
    const float* __restrict__ Wk, const float* __restrict__ Wv,
    const float* __restrict__ Wo,
    __hip_bfloat16* __restrict__ xb, __hip_bfloat16* __restrict__ Wb)
{
    const int idx = blockIdx.x * 256 + threadIdx.x;
    if (idx < 8192 * 128) {
        const int row = idx >> 7, c = (idx & 127) << 2;
        const int bi = row >> 11, ni = row & 2047;
        float4 v = *(const float4*)(x + ((size_t)(ni * NB + bi)) * DMODEL + c);
        uint2 u; u.x = bfpack(v.x, v.y); u.y = bfpack(v.z, v.w);
        *(uint2*)((short*)xb + (size_t)row * 512 + c) = u;
    } else {
        const int j = idx - 8192 * 128;
        const int row = j >> 7, c = (j & 127) << 2;
        const float* src = (row < 512) ? Wq : (row < 1024) ? Wk
                         : (row < 1536) ? Wv : Wo;
        const int rr = row & 511;
        float4 v = *(const float4*)(src + (size_t)rr * 512 + c);
        uint2 u; u.x = bfpack(v.x, v.y); u.y = bfpack(v.z, v.w);
        *(uint2*)((short*)Wb + (size_t)row * 512 + c) = u;
    }
}

// ---------------------------------------------------------------------------
// Kernel 1: QKV projection, pure-bf16 MFMA GEMM. 128x128 tile, BK=64.
// XCD-aware remap: all 12 col-tiles of a row-tile pin to one XCD so the
// x-tile is read from L2, not HBM, by 11 of the 12 blocks.
// ---------------------------------------------------------------------------
__global__ __launch_bounds__(256) void k1_qkv(
    const __hip_bfloat16* __restrict__ xb, const float* __restrict__ rope,
    const __hip_bfloat16* __restrict__ Wb,
    __hip_bfloat16* __restrict__ Qw, __hip_bfloat16* __restrict__ Kw,
    __hip_bfloat16* __restrict__ Vt)
{
    __shared__ short As[128 * 72];
    __shared__ short Bs[128 * 72];
    const int t = threadIdx.x;
    const int w = t >> 6, L = t & 63, lo = L & 15, g = L >> 4;
    const int mh = (w >> 1) << 6, nh = (w & 1) << 6;

    // XCD-aware remap: linear id -> (row_blk, col_blk), same row_blk => same XCD
    const int lid = (int)(blockIdx.y * gridDim.x + blockIdx.x);
    const int xcd = lid & 7, slot = lid >> 3;
    const int row_blk = xcd * 8 + (slot & 7);     // 0..63
    const int col_blk = slot >> 3;                // 0..11
    const int row0 = row_blk * 128, col0 = col_blk * 128;

    f32x4 acc[4][4] = {};
    for (int k0 = 0; k0 < DMODEL; k0 += 64) {
        __syncthreads();
#pragma unroll
        for (int c = 0; c < 4; ++c) {
            const int idx = c * 256 + t;
            const int m = idx >> 3, kb = idx & 7;
            *(uint4*)&As[m * 72 + kb * 8] =
                *(const uint4*)((const short*)xb + (size_t)(row0 + m) * 512 + k0 + kb * 8);
            *(uint4*)&Bs[m * 72 + kb * 8] =
                *(const uint4*)((const short*)Wb + (size_t)(col0 + m) * 512 + k0 + kb * 8);
        }
        __syncthreads();
#pragma unroll
        for (int ks = 0; ks < 2; ++ks) {
            bf16x8 af[4], bfr[4];
#pragma unroll
            for (int mi = 0; mi < 4; ++mi)
                af[mi] = *(const bf16x8*)&As[(mh + mi * 16 + lo) * 72 + ks * 32 + g * 8];
#pragma unroll
            for (int ni = 0; ni < 4; ++ni)
                bfr[ni] = *(const bf16x8*)&Bs[(nh + ni * 16 + lo) * 72 + ks * 32 + g * 8];
#pragma unroll
            for (int mi = 0; mi < 4; ++mi)
#pragma unroll
                for (int ni = 0; ni < 4; ++ni)
                    acc[mi][ni] = __builtin_amdgcn_mfma_f32_16x16x32_bf16(
                        af[mi], bfr[ni], acc[mi][ni], 0, 0, 0);
        }
    }

    const int region = col0 >> 9;          // 0=Q 1=K 2,3=V
    const int cbase = col0 & 511;
    const int bi = row0 >> 11;
    const int ni0 = row0 & 2047;
    const float SC = 0.125f * 1.44269504088896f;   // attn scale * log2(e) into Q
    if (region < 2) {
        __hip_bfloat16* outp = (region == 0) ? Qw : Kw;
        const float qs = (region == 0) ? SC : 1.0f;
#pragma unroll
        for (int ni = 0; ni < 4; ++ni) {
            const int c = cbase + nh + ni * 16 + lo;
            const int h = c >> 6, e = c & 63;
            const float sgn = (e & 1) ? 1.0f : -1.0f;
#pragma unroll
            for (int mi = 0; mi < 4; ++mi) {
#pragma unroll
                for (int r = 0; r < 4; ++r) {
                    const int nseq = ni0 + mh + mi * 16 + g * 4 + r;
                    const float f = rope[((size_t)bi * NSEQ + nseq) * DH + e];
                    const float v = acc[mi][ni][r];
                    const float p = __shfl_xor(v, 1);   // rotate-half partner
                    const float rv = (v * __cosf(f) + sgn * p * __sinf(f)) * qs;
                    *((short*)outp + ((size_t)(bi * NH + h) * NSEQ + nseq) * DH + e) = f2bf_r(rv);
                }
            }
        }
    } else {
        // V transposed: Vt[(b*NH+h)*DH + d][nseq]
#pragma unroll
        for (int ni = 0; ni < 4; ++ni) {
            const int c = cbase + nh + ni * 16 + lo;
            const int h = c >> 6, e = c & 63;
#pragma unroll
            for (int mi = 0; mi < 4; ++mi) {
                const int nb = ni0 + mh + mi * 16 + g * 4;
                uint2 u;
                u.x = bfpack(acc[mi][ni][0], acc[mi][ni][1]);
                u.y = bfpack(acc[mi][ni][2], acc[mi][ni][3]);
                *(uint2*)((short*)Vt + ((size_t)(bi * NH + h) * DH + e) * NSEQ + nb) = u;
            }
        }
    }
}

// ---------------------------------------------------------------------------
// Kernel 2: causal flash attention, bf16 MFMA, double-buffered LDS staging.
// XCD-aware remap: bh = (lid%8)*4 + (lid/8)%4 pins all 16 blocks of a head
// to one XCD -> K/V (2 MB per XCD for its 4 heads) stay L2-resident and
// staging loads become ~200-cyc L2 hits hidden by the register prefetch.
// Balanced pairing: block handles q-tiles {p, 31-p} = 33 key-tiles each.
// ---------------------------------------------------------------------------
__global__ __launch_bounds__(256) void k2_attn(
    const __hip_bfloat16* __restrict__ Qw, const __hip_bfloat16* __restrict__ Kw,
    const __hip_bfloat16* __restrict__ Vt, const float* __restrict__ head_scale,
    __hip_bfloat16* __restrict__ Ob)
{
    __shared__ short sK[2][64 * 72];
    __shared__ short sV[2][64 * 72];
    __shared__ short sP[4][16 * 72];
    __shared__ float sA[4][16];
    __shared__ float sLl[4][16];

    const int t = threadIdx.x;
    const int w = t >> 6, L = t & 63, lo = L & 15, g = L >> 4;

    // XCD-aware remap (grid is 512 linear blocks)
    const int lid = (int)blockIdx.x;
    const int slot = lid >> 3;
    const int bh = (lid & 7) * 4 + (slot & 3);    // 0..31, pinned per XCD
    const int pairIdx = slot >> 2;                // 0..15
    const int bi = bh >> 3, h = bh & 7;

    const size_t baseQK = (size_t)bh * (NSEQ * DH);
    const size_t baseV  = (size_t)bh * (DH * NSEQ);
    const float hs = head_scale[h];
    const int sm = t >> 3, skb = t & 7;   // staging: row sm(+32c), 16B chunk skb

#pragma unroll 1
    for (int phase = 0; phase < 2; ++phase) {
        const int qg = phase ? 31 - pairIdx : pairIdx;
        const int q0 = qg << 6;
        const int qw16 = q0 + (w << 4);
        const __hip_bfloat16* qp = Qw + baseQK + (size_t)(qw16 + lo) * DH + g * 8;
        const bf16x8 qb0 = *(const bf16x8*)qp;
        const bf16x8 qb1 = *(const bf16x8*)(qp + 32);
        f32x4 acc[4] = {};
        float m_i = -1e30f, l_i = 0.f;
        const int nkt = qg + 1;

        // preload tile 0 into regs, then buffer 0
        uint4 kr[2], vr[2];
#pragma unroll
        for (int c = 0; c < 2; ++c) {
            const int m = sm + c * 32;
            kr[c] = *(const uint4*)((const short*)Kw + baseQK + (size_t)m * DH + skb * 8);
            vr[c] = *(const uint4*)((const short*)Vt + baseV + (size_t)m * NSEQ + skb * 8);
        }
        __syncthreads();   // protect buffers still being read by prior phase
#pragma unroll
        for (int c = 0; c < 2; ++c) {
            const int m = sm + c * 32;
            *(uint4*)&sK[0][m * 72 + skb * 8] = kr[c];
            *(uint4*)&sV[0][m * 72 + skb * 8] = vr[c];
        }

        for (int kt = 0; kt < nkt; ++kt) {
            const int cur = kt & 1;
            if (kt + 1 < nkt) {   // prefetch next tile into regs
                const int k0n = (kt + 1) << 6;
#pragma unroll
                for (int c = 0; c < 2; ++c) {
                    const int m = sm + c * 32;
                    kr[c] = *(const uint4*)((const short*)Kw + baseQK + (size_t)(k0n + m) * DH + skb * 8);
                    vr[c] = *(const uint4*)((const short*)Vt + baseV + (size_t)m * NSEQ + k0n + skb * 8);
                }
            }
            __syncthreads();   // buf[cur] fully written; prior reads of buf[cur^1] done

            const bool diag = (kt == qg);
            const int mlim = diag ? w : 3;
            f32x4 s[4];
#pragma unroll
            for (int mt = 0; mt < 4; ++mt) {
                if (mt <= mlim) {
                    bf16x8 ka0 = *(const bf16x8*)&sK[cur][(mt * 16 + lo) * 72 + g * 8];
                    bf16x8 ka1 = *(const bf16x8*)&sK[cur][(mt * 16 + lo) * 72 + 32 + g * 8];
                    f32x4 z = {};
                    z = __builtin_amdgcn_mfma_f32_16x16x32_bf16(ka0, qb0, z, 0, 0, 0);
                    s[mt] = __builtin_amdgcn_mfma_f32_16x16x32_bf16(ka1, qb1, z, 0, 0, 0);
                    if (diag && mt == mlim) {
#pragma unroll
                        for (int r = 0; r < 4; ++r)
                            if ((g * 4 + r) > lo) s[mt][r] = -1e30f;
                    }
                } else {
                    s[mt] = (f32x4){ -1e30f, -1e30f, -1e30f, -1e30f };
                }
            }

            // online softmax: lane owns q=lo; keys spread over (mt, r, quad)
            float mx = s[0][0];
#pragma unroll
            for (int mt = 0; mt < 4; ++mt)
#pragma unroll
                for (int r = 0; r < 4; ++r)
                    mx = fmaxf(mx, s[mt][r]);
            mx = fmaxf(mx, __shfl_xor(mx, 16));
            mx = fmaxf(mx, __shfl_xor(mx, 32));
            const float mnew = fmaxf(m_i, mx);
            const float alpha = exp2f(m_i - mnew);
            m_i = mnew;
            float rs = 0.f;
#pragma unroll
            for (int mt = 0; mt < 4; ++mt) {
                const float p0 = exp2f(s[mt][0] - mnew);
                const float p1 = exp2f(s[mt][1] - mnew);
                const float p2 = exp2f(s[mt][2] - mnew);
                const float p3 = exp2f(s[mt][3] - mnew);
                rs += (p0 + p1) + (p2 + p3);
                uint2 u; u.x = bfpack(p0, p1); u.y = bfpack(p2, p3);
                *(uint2*)&sP[w][lo * 72 + mt * 16 + g * 4] = u;
            }
            rs += __shfl_xor(rs, 16);
            rs += __shfl_xor(rs, 32);
            l_i = l_i * alpha + rs;
            if (g == 0) sA[w][lo] = alpha;
            const f32x4 al = *(const f32x4*)&sA[w][g * 4];
#pragma unroll
            for (int dt = 0; dt < 4; ++dt) acc[dt] *= al;

            const bf16x8 pa0 = *(const bf16x8*)&sP[w][lo * 72 + g * 8];
            if (!(diag && w < 2)) {
                const bf16x8 pa1 = *(const bf16x8*)&sP[w][lo * 72 + 32 + g * 8];
#pragma unroll
                for (int dt = 0; dt < 4; ++dt) {
                    bf16x8 vb0 = *(const bf16x8*)&sV[cur][(dt * 16 + lo) * 72 + g * 8];
                    bf16x8 vb1 = *(const bf16x8*)&sV[cur][(dt * 16 + lo) * 72 + 32 + g * 8];
                    acc[dt] = __builtin_amdgcn_mfma_f32_16x16x32_bf16(pa0, vb0, acc[dt], 0, 0, 0);
                    acc[dt] = __builtin_amdgcn_mfma_f32_16x16x32_bf16(pa1, vb1, acc[dt], 0, 0, 0);
                }
            } else {   // keys 32..63 fully masked on diagonal for waves 0,1
#pragma unroll
                for (int dt = 0; dt < 4; ++dt) {
                    bf16x8 vb0 = *(const bf16x8*)&sV[cur][(dt * 16 + lo) * 72 + g * 8];
                    acc[dt] = __builtin_amdgcn_mfma_f32_16x16x32_bf16(pa0, vb0, acc[dt], 0, 0, 0);
                }
            }

            if (kt + 1 < nkt) {   // write prefetched tile into the other buffer
#pragma unroll
                for (int c = 0; c < 2; ++c) {
                    const int m = sm + c * 32;
                    *(uint4*)&sK[cur ^ 1][m * 72 + skb * 8] = kr[c];
                    *(uint4*)&sV[cur ^ 1][m * 72 + skb * 8] = vr[c];
                }
            }
        }

        // per-phase epilogue
        if (g == 0) sLl[w][lo] = l_i;
        const f32x4 lv = *(const f32x4*)&sLl[w][g * 4];
#pragma unroll
        for (int r = 0; r < 4; ++r) {
            const int q = q0 + (w << 4) + g * 4 + r;
            const float f = hs / lv[r];
#pragma unroll
            for (int dt = 0; dt < 4; ++dt)
                *((short*)Ob + ((size_t)bi * NSEQ + q) * DMODEL + h * DH + dt * 16 + lo) =
                    f2bf_r(acc[dt][r] * f);
        }
    }
}

// ---------------------------------------------------------------------------
// Kernel 3: out projection, pure-bf16 MFMA, same skeleton as k1 (XCD remap).
// ---------------------------------------------------------------------------
__global__ __launch_bounds__(256) void k3_proj(
    const __hip_bfloat16* __restrict__ Ob, const __hip_bfloat16* __restrict__ Wob,
    const float* __restrict__ bo, float* __restrict__ C2)
{
    __shared__ short As[128 * 72];
    __shared__ short Bs[128 * 72];
    const int t = threadIdx.x;
    const int w = t >> 6, L = t & 63, lo = L & 15, g = L >> 4;
    const int mh = (w >> 1) << 6, nh = (w & 1) << 6;

    const int lid = (int)(blockIdx.y * gridDim.x + blockIdx.x);
    const int xcd = lid & 7, slot = lid >> 3;
    const int row_blk = xcd * 8 + (slot & 7);     // 0..63
    const int col_blk = slot >> 3;                // 0..3
    const int row0 = row_blk * 128, col0 = col_blk * 128;

    f32x4 acc[4][4] = {};
    for (int k0 = 0; k0 < DMODEL; k0 += 64) {
        __syncthreads();
#pragma unroll
        for (int c = 0; c < 4; ++c) {
            const int idx = c * 256 + t;
            const int m = idx >> 3, kb = idx & 7;
            *(uint4*)&As[m * 72 + kb * 8] =
                *(const uint4*)((const short*)Ob + (size_t)(row0 + m) * 512 + k0 + kb * 8);
            *(uint4*)&Bs[m * 72 + kb * 8] =
                *(const uint4*)((const short*)Wob + (size_t)(col0 + m) * 512 + k0 + kb * 8);
        }
        __syncthreads();
#pragma unroll
        for (int ks = 0; ks < 2; ++ks) {
            bf16x8 af[4], bfr[4];
#pragma unroll
            for (int mi = 0; mi < 4; ++mi)
                af[mi] = *(const bf16x8*)&As[(mh + mi * 16 + lo) * 72 + ks * 32 + g * 8];
#pragma unroll
            for (int ni = 0; ni < 4; ++ni)
                bfr[ni] = *(const bf16x8*)&Bs[(nh + ni * 16 + lo) * 72 + ks * 32 + g * 8];
#pragma unroll
            for (int mi = 0; mi < 4; ++mi)
#pragma unroll
                for (int ni = 0; ni < 4; ++ni)
                    acc[mi][ni] = __builtin_amdgcn_mfma_f32_16x16x32_bf16(
                        af[mi], bfr[ni], acc[mi][ni], 0, 0, 0);
        }
    }
#pragma unroll
    for (int ni = 0; ni < 4; ++ni) {
        const int c = col0 + nh + ni * 16 + lo;
        const float b = bo[c];
#pragma unroll
        for (int mi = 0; mi < 4; ++mi) {
#pragma unroll
            for (int r = 0; r < 4; ++r) {
                const int m = row0 + mh + mi * 16 + g * 4 + r;
                C2[(size_t)m * DMODEL + c] = acc[mi][ni][r] + b;
            }
        }
    }
}

// ---------------------------------------------------------------------------
// Kernel 4: LayerNorm over dim 512 + ls_scale + transpose store to (n,b,d)
// ---------------------------------------------------------------------------
__global__ __launch_bounds__(256) void k4_ln(
    const float* __restrict__ C2, const float* __restrict__ g,
    const float* __restrict__ bln, const float* __restrict__ ls,
    float* __restrict__ out)
{
    const int m = blockIdx.x;
    const int bi = m >> 11, ni = m & (NSEQ - 1);
    const float* row = C2 + (size_t)m * DMODEL;
    const int t = threadIdx.x;
    float v0 = row[t], v1 = row[t + 256];
    float s = v0 + v1, sq2 = v0 * v0 + v1 * v1;
#pragma unroll
    for (int off = 32; off > 0; off >>= 1) {
        s += __shfl_down(s, off);
        sq2 += __shfl_down(sq2, off);
    }
    __shared__ float red[8];
    const int wid = t >> 6;
    if ((t & 63) == 0) { red[wid] = s; red[wid + 4] = sq2; }
    __syncthreads();
    s = red[0] + red[1] + red[2] + red[3];
    sq2 = red[4] + red[5] + red[6] + red[7];
    const float mean = s * (1.f / 512.f);
    const float var = sq2 * (1.f / 512.f) - mean * mean;
    const float rstd = rsqrtf(var + 1e-5f);
    float* ob = out + ((size_t)ni * NB + bi) * DMODEL;
    ob[t]       = ((v0 - mean) * rstd * g[t]       + bln[t])       * ls[t];
    ob[t + 256] = ((v1 - mean) * rstd * g[t + 256] + bln[t + 256]) * ls[t + 256];
}

// ---------------------------------------------------------------------------
extern "C" void kernel_launch(void* const* d_in, const int* in_sizes, int n_in,
                              void* d_out, int out_size, void* d_ws, size_t ws_size,
                              hipStream_t stream) {
    const float* x          = (const float*)d_in[0];
    const float* rope       = (const float*)d_in[1];
    const float* Wq         = (const float*)d_in[2];
    const float* Wk         = (const float*)d_in[3];
    const float* Wv         = (const float*)d_in[4];
    const float* Wo         = (const float*)d_in[5];
    const float* bo         = (const float*)d_in[6];
    const float* ln_g       = (const float*)d_in[7];
    const float* ln_b       = (const float*)d_in[8];
    const float* head_scale = (const float*)d_in[9];
    const float* ls_scale   = (const float*)d_in[10];
    float* out = (float*)d_out;

    char* wsb = (char*)d_ws;
    __hip_bfloat16* xb  = (__hip_bfloat16*)(wsb);                       // 8 MB
    __hip_bfloat16* Wb  = (__hip_bfloat16*)(wsb + ((size_t) 8 << 20));  // 2 MB
    __hip_bfloat16* Qw  = (__hip_bfloat16*)(wsb + ((size_t)10 << 20));  // 8 MB
    __hip_bfloat16* Kw  = (__hip_bfloat16*)(wsb + ((size_t)18 << 20));  // 8 MB
    __hip_bfloat16* Vt  = (__hip_bfloat16*)(wsb + ((size_t)26 << 20));  // 8 MB
    __hip_bfloat16* Ob  = (__hip_bfloat16*)(wsb + ((size_t)34 << 20));  // 8 MB
    float*          C2  = (float*)(wsb + ((size_t)10 << 20));           // 16 MB, overlaps Q/K
    __hip_bfloat16* Wob = Wb + (size_t)1536 * 512;

    k0_convert<<<5120, 256, 0, stream>>>(x, Wq, Wk, Wv, Wo, xb, Wb);
    k1_qkv<<<dim3(64, 12), 256, 0, stream>>>(xb, rope, Wb, Qw, Kw, Vt);
    k2_attn<<<512, 256, 0, stream>>>(Qw, Kw, Vt, head_scale, Ob);
    k3_proj<<<dim3(64, 4), 256, 0, stream>>>(Ob, Wob, bo, C2);
    k4_ln<<<MROWS, 256, 0, stream>>>(C2, ln_g, ln_b, ls_scale, out);
}